// Round 15
// baseline (229.980 us; speedup 1.0000x reference)
//
#include <hip/hip_runtime.h>
#include <stdint.h>

typedef unsigned long long u64;
typedef unsigned int u32;

#define Nn 32
#define Cc 64
#define Hh 128
#define Ww 128
#define HPAD 130
#define WPAD 130
#define NHW_TOT (Nn*Hh*Ww)
#define NBIN 16

// ---------------------------------------------------------------- BN finalize (in-kernel, per-lane c)
__device__ __forceinline__ float2 compute_ab(const u64* __restrict__ sum, const u64* __restrict__ sq,
        const float* __restrict__ g, const float* __restrict__ bet, int c) {
    long long Sv = 0, Qv = 0;
    #pragma unroll
    for (int b = 0; b < NBIN; ++b) {
        Sv += (long long)sum[b * 64 + c];
        Qv += (long long)sq[b * 64 + c];
    }
    double mean = (double)Sv / (double)NHW_TOT;
    double var = (double)Qv / (double)NHW_TOT - mean * mean;
    double invstd = 1.0 / sqrt(var + 1e-5);
    double a = (double)g[c] * invstd;
    double b_ = (double)bet[c] - a * mean;
    return make_float2((float)a, (float)b_);
}

// ---------------------------------------------------------------- prep: pack_x (blocks<512) + pack_w + zeroing
#define BORDER_PER_IMG 516              // 2*130 (top+bottom rows) + 2*128 (side cols)
#define BORDER_TOT (Nn * BORDER_PER_IMG)
#define PREP_EXTRA (1152 + 2 * BORDER_TOT + 4 * NBIN * 64)

__global__ __launch_bounds__(256) void prep_kernel(const float* __restrict__ x,
        const float* __restrict__ w1, const float* __restrict__ w2,
        u64* __restrict__ xpad, u64* __restrict__ ypad,
        u64* __restrict__ w1b, u64* __restrict__ w2b, u64* __restrict__ stats) {
    if (blockIdx.x < 512) {
        // ---- pack sign(x) -> u64/pixel, float4 loads
        int t = blockIdx.x * 256 + threadIdx.x;
        int P = t * 4;
        int row = P >> 7, w0 = P & 127;
        int n = row >> 7, h = row & 127;
        const float4* xp4 = (const float4*)(x + ((size_t)n * Cc * Hh + h) * Ww + w0);
        u32 lo0 = 0, lo1 = 0, lo2 = 0, lo3 = 0, hi0 = 0, hi1 = 0, hi2 = 0, hi3 = 0;
        #pragma unroll 8
        for (int c = 0; c < 32; ++c) {
            float4 v = xp4[c * (Hh * Ww / 4)];
            lo0 |= (__float_as_uint(v.x) >> 31) << c;
            lo1 |= (__float_as_uint(v.y) >> 31) << c;
            lo2 |= (__float_as_uint(v.z) >> 31) << c;
            lo3 |= (__float_as_uint(v.w) >> 31) << c;
        }
        #pragma unroll 8
        for (int c = 32; c < 64; ++c) {
            float4 v = xp4[c * (Hh * Ww / 4)];
            hi0 |= (__float_as_uint(v.x) >> 31) << (c - 32);
            hi1 |= (__float_as_uint(v.y) >> 31) << (c - 32);
            hi2 |= (__float_as_uint(v.z) >> 31) << (c - 32);
            hi3 |= (__float_as_uint(v.w) >> 31) << (c - 32);
        }
        u64* dst = xpad + ((size_t)n * HPAD + h + 1) * WPAD + w0 + 1;
        dst[0] = ((u64)hi0 << 32) | lo0;
        dst[1] = ((u64)hi1 << 32) | lo1;
        dst[2] = ((u64)hi2 << 32) | lo2;
        dst[3] = ((u64)hi3 << 32) | lo3;
    } else {
        // ---- grid-stride over: weight packing (1152) + border/stat zeroing
        int t = (blockIdx.x - 512) * 256 + threadIdx.x;
        int stride = (gridDim.x - 512) * 256;
        for (int i = t; i < PREP_EXTRA; i += stride) {
            if (i < 1152) {
                int set = i / 576, idx = i - set * 576;
                const float* src = set ? w2 : w1;
                u64* db = set ? w2b : w1b;
                int co = idx / 9, tap = idx - co * 9;            // co-stride 576
                const float* p = src + (size_t)co * 576 + tap;   // [co][ci][kh][kw], ci stride 9
                u32 lo = 0, hi = 0;
                #pragma unroll
                for (int ci = 0; ci < 32; ++ci)
                    lo |= (__float_as_uint(p[ci * 9]) >> 31) << ci;
                #pragma unroll
                for (int ci = 32; ci < 64; ++ci)
                    hi |= (__float_as_uint(p[ci * 9]) >> 31) << (ci - 32);
                db[idx] = ((u64)hi << 32) | lo;
            } else if (i < 1152 + 2 * BORDER_TOT) {
                int z = i - 1152;
                u64* buf = (z < BORDER_TOT) ? xpad : ypad;
                int k = (z < BORDER_TOT) ? z : z - BORDER_TOT;
                int img = k / BORDER_PER_IMG, j = k - img * BORDER_PER_IMG;
                size_t base = (size_t)img * HPAD * WPAD;
                size_t off;
                if (j < 130)      off = j;                                     // row 0
                else if (j < 260) off = (size_t)(HPAD - 1) * WPAD + (j - 130); // row 129
                else {
                    int k2 = j - 260;
                    off = (size_t)(1 + (k2 >> 1)) * WPAD + ((k2 & 1) ? (WPAD - 1) : 0);
                }
                buf[base + off] = 0ull;
            } else {
                stats[i - 1152 - 2 * BORDER_TOT] = 0ull;
            }
        }
    }
}

// ---------------------------------------------------------------- conv core: lane = co, b128 window loads
__device__ __forceinline__ void conv4(const u64* __restrict__ L0, const u64* __restrict__ L1,
                                      const u64* __restrict__ L2, int w,
                                      const u64 W[9], int corrMid, int v[4]) {
    u64 a[6], b[6], c[6];
    #pragma unroll
    for (int j = 0; j < 3; ++j) {       // 9 x ds_read_b128 instead of 18 x b64
        ulonglong2 pa = *(const ulonglong2*)&L0[w + 2 * j];
        ulonglong2 pb = *(const ulonglong2*)&L1[w + 2 * j];
        ulonglong2 pc = *(const ulonglong2*)&L2[w + 2 * j];
        a[2 * j] = pa.x; a[2 * j + 1] = pa.y;
        b[2 * j] = pb.x; b[2 * j + 1] = pb.y;
        c[2 * j] = pc.x; c[2 * j + 1] = pc.y;
    }
    #pragma unroll
    for (int px = 0; px < 4; ++px) {
        int p0 = __popcll(a[px] ^ W[0]) + __popcll(a[px + 1] ^ W[1]) + __popcll(a[px + 2] ^ W[2]);
        int p1 = __popcll(b[px] ^ W[3]) + __popcll(b[px + 1] ^ W[4]) + __popcll(b[px + 2] ^ W[5]);
        int p2 = __popcll(c[px] ^ W[6]) + __popcll(c[px + 1] ^ W[7]) + __popcll(c[px + 2] ^ W[8]);
        v[px] = 576 - 2 * (p0 + p1 + p2) - corrMid;
    }
}

struct LaneCtx {
    u64 W[9];
    int corrMid, corrW0, corrW127;
};

__device__ __forceinline__ void lane_setup(LaneCtx& C, const u64* __restrict__ wb,
                                           int lane, int h) {
    #pragma unroll
    for (int t = 0; t < 9; ++t) C.W[t] = wb[lane * 9 + t];
    int wc[9];
    #pragma unroll
    for (int t = 0; t < 9; ++t) wc[t] = 64 - 2 * __popcll(C.W[t]);
    int tT = wc[0] + wc[1] + wc[2], tB = wc[6] + wc[7] + wc[8];
    int tL = wc[0] + wc[3] + wc[6], tR = wc[2] + wc[5] + wc[8];
    bool fT = (h == 0), fB = (h == 127);
    C.corrMid  = (fT ? tT : 0) + (fB ? tB : 0);
    C.corrW0   = tL - (fT ? wc[0] : 0) - (fB ? wc[6] : 0);
    C.corrW127 = tR - (fT ? wc[2] : 0) - (fB ? wc[8] : 0);
}

// common half-row window load: rows hp*2..hp*2+3, cols half*64..half*64+65
__device__ __forceinline__ void load_win(u64* __restrict__ win, const u64* __restrict__ inpad,
                                         int n, int hp, int half, int tid) {
    const u64* src = inpad + ((size_t)n * HPAD + hp * 2) * WPAD + half * 64;
    for (int i = tid; i < 264; i += 128) {
        int r = i / 66, c = i - r * 66;
        win[r * 68 + c] = src[(size_t)r * WPAD + c];
    }
}

// ---------------------------------------------------------------- conv + exact BN stats (+ optional v16 spill)
// block = 128 threads = 2 waves; wave = half-row (64 px). blk = n*128 + hp*2 + half
template<bool SPILL>
__global__ __launch_bounds__(128) void conv_statsT(const u64* __restrict__ inpad,
        const u64* __restrict__ wb, u64* __restrict__ gsum, u64* __restrict__ gsq,
        short* __restrict__ v16) {
    __shared__ u64 win[4 * 68];
    __shared__ int r32[256];
    int tid = threadIdx.x;
    int lane = tid & 63;
    int wv = __builtin_amdgcn_readfirstlane(tid >> 6);   // 0/1
    int blk = blockIdx.x;
    int half = blk & 1;
    int hp = (blk >> 1) & 63;
    int n = blk >> 7;
    int h = hp * 2 + wv;
    load_win(win, inpad, n, hp, half, tid);
    LaneCtx C;
    lane_setup(C, wb, lane, h);
    __syncthreads();
    const u64* L0 = &win[wv * 68];
    const u64* L1 = L0 + 68;
    const u64* L2 = L0 + 136;
    short* vrow = SPILL ? (v16 + (((size_t)(n * Hh + h) * Ww) + half * 64) * 64 + lane) : nullptr;
    int s = 0, q = 0;
    for (int w = 0; w < 64; w += 4) {
        int v[4];
        conv4(L0, L1, L2, w, C.W, C.corrMid, v);
        if (half == 0 && w == 0)  v[0] -= C.corrW0;
        if (half == 1 && w == 60) v[3] -= C.corrW127;
        #pragma unroll
        for (int px = 0; px < 4; ++px) {
            s += v[px];
            q += __mul24(v[px], v[px]);
            if (SPILL) vrow[(size_t)(w + px) * 64] = (short)v[px];
        }
    }
    __syncthreads();
    r32[wv * 64 + lane] = s;
    r32[128 + wv * 64 + lane] = q;
    __syncthreads();
    if (wv == 0) {
        int S = r32[lane] + r32[64 + lane];
        int Q = r32[128 + lane] + r32[192 + lane];
        int bin = blk & (NBIN - 1);
        atomicAdd(&gsum[bin * 64 + lane], (u64)(long long)S);
        atomicAdd(&gsq[bin * 64 + lane], (u64)(long long)Q);
    }
}

// ---------------------------------------------------------------- sign(bn1(v16)) -> ballot pack (memory pass)
// block = 256 th = 4 waves; wave = half-row. blk covers rows blk*2, blk*2+1
__global__ __launch_bounds__(256) void signpack_v(const short* __restrict__ v16,
        const u64* __restrict__ sum, const u64* __restrict__ sq,
        const float* __restrict__ g, const float* __restrict__ bet,
        u64* __restrict__ ypad) {
    int tid = threadIdx.x;
    int lane = tid & 63;
    int wv = tid >> 6;
    int grow = blockIdx.x * 2 + (wv >> 1);
    int base = (wv & 1) * 64;
    int n = grow >> 7, h = grow & 127;
    float2 ab = compute_ab(sum, sq, g, bet, lane);
    const short* vr = v16 + ((size_t)grow * Ww + base) * 64;
    u64* drow = ypad + ((size_t)n * HPAD + h + 1) * WPAD + 1;
    u64 myw = 0;
    #pragma unroll 8
    for (int px = 0; px < 64; ++px) {
        float tv = fmaf((float)vr[(size_t)px * 64 + lane], ab.x, ab.y);
        u64 bal = __ballot(tv < 0.0f);
        if (lane == px) myw = bal;
    }
    drow[base + lane] = myw;
}

// ---------------------------------------------------------------- fallback: conv1 recompute signpack (no spill)
__global__ __launch_bounds__(128) void signpack_h(const u64* __restrict__ inpad,
        const u64* __restrict__ wb, const u64* __restrict__ sum, const u64* __restrict__ sq,
        const float* __restrict__ g, const float* __restrict__ bet,
        u64* __restrict__ ypad) {
    __shared__ u64 win[4 * 68];
    int tid = threadIdx.x;
    int lane = tid & 63;
    int wv = __builtin_amdgcn_readfirstlane(tid >> 6);
    int blk = blockIdx.x;
    int half = blk & 1;
    int hp = (blk >> 1) & 63;
    int n = blk >> 7;
    int h = hp * 2 + wv;
    load_win(win, inpad, n, hp, half, tid);
    LaneCtx C;
    lane_setup(C, wb, lane, h);
    float2 ab = compute_ab(sum, sq, g, bet, lane);
    __syncthreads();
    const u64* L0 = &win[wv * 68];
    const u64* L1 = L0 + 68;
    const u64* L2 = L0 + 136;
    u64 myw = 0;
    for (int w = 0; w < 64; w += 4) {
        int v[4];
        conv4(L0, L1, L2, w, C.W, C.corrMid, v);
        if (half == 0 && w == 0)  v[0] -= C.corrW0;
        if (half == 1 && w == 60) v[3] -= C.corrW127;
        #pragma unroll
        for (int px = 0; px < 4; ++px) {
            float t = fmaf((float)v[px], ab.x, ab.y);
            u64 bal = __ballot(t < 0.0f);
            if (lane == w + px) myw = bal;
        }
    }
    ypad[((size_t)n * HPAD + h + 1) * WPAD + 1 + half * 64 + lane] = myw;
}

// ---------------------------------------------------------------- conv2 + bn2 + residual + hardtanh
// final9: ALL 16 x-loads (both chunks) issued at kernel entry, before window
// staging, so HBM latency hides under staging + lane_setup + chunk-0 conv.
__global__ __launch_bounds__(128) void final9_kernel(const u64* __restrict__ inpad,
        const u64* __restrict__ wb, const u64* __restrict__ sum, const u64* __restrict__ sq,
        const float* __restrict__ g, const float* __restrict__ bet,
        const float* __restrict__ x, float* __restrict__ out) {
    __shared__ u64 win[4 * 68];
    __shared__ short T[2][64 * 36];
    __shared__ float2 absh[64];
    int tid = threadIdx.x;
    int lane = tid & 63;
    int wv = __builtin_amdgcn_readfirstlane(tid >> 6);
    int blk = blockIdx.x;
    int half = blk & 1;
    int hp = (blk >> 1) & 63;
    int n = blk >> 7;
    int h = hp * 2 + wv;
    int p4 = lane & 7;
    int cosub = lane >> 3;
    // lane's base address: [n][cosub][h][half*64 + p4*4]
    size_t base2 = (((size_t)n * Cc + cosub) * Hh + h) * Ww + half * 64 + p4 * 4;
    // ---- issue-early: all 16 float4 x-loads (chunk0: +0, chunk1: +32)
    float4 xv[16];
    #pragma unroll
    for (int st = 0; st < 8; ++st) {
        const float* px0 = x + base2 + (size_t)st * 8 * (Hh * Ww);
        xv[st]     = *(const float4*)(px0);
        xv[8 + st] = *(const float4*)(px0 + 32);
    }
    load_win(win, inpad, n, hp, half, tid);
    LaneCtx C;
    lane_setup(C, wb, lane, h);
    if (tid < 64) absh[tid] = compute_ab(sum, sq, g, bet, tid);
    __syncthreads();
    const u64* L0 = &win[wv * 68];
    const u64* L1 = L0 + 68;
    const u64* L2 = L0 + 136;
    short* Tw = T[wv];
    #pragma unroll
    for (int chunk = 0; chunk < 2; ++chunk) {
        int w0 = chunk * 32;
        // ---- conv the 32-px chunk into the wave-private tile
        for (int w = w0; w < w0 + 32; w += 4) {
            int v[4];
            conv4(L0, L1, L2, w, C.W, C.corrMid, v);
            if (half == 0 && w == 0)  v[0] -= C.corrW0;
            if (half == 1 && w == 60) v[3] -= C.corrW127;
            short4 sv;
            sv.x = (short)v[0]; sv.y = (short)v[1]; sv.z = (short)v[2]; sv.w = (short)v[3];
            *(short4*)&Tw[lane * 36 + (w & 31)] = sv;
        }
        // ---- flush with preloaded x (addresses recomputed, not stored)
        #pragma unroll 8
        for (int st = 0; st < 8; ++st) {
            int co = st * 8 + cosub;
            short4 tv = *(const short4*)&Tw[co * 36 + p4 * 4];
            float2 cab = absh[co];
            float4 xw = xv[chunk * 8 + st];
            size_t idx = base2 + (size_t)st * 8 * (Hh * Ww) + w0;
            float4 yv;
            yv.x = fminf(1.0f, fmaxf(-1.0f, fmaf((float)tv.x, cab.x, cab.y) + xw.x));
            yv.y = fminf(1.0f, fmaxf(-1.0f, fmaf((float)tv.y, cab.x, cab.y) + xw.y));
            yv.z = fminf(1.0f, fmaxf(-1.0f, fmaf((float)tv.z, cab.x, cab.y) + xw.z));
            yv.w = fminf(1.0f, fmaxf(-1.0f, fmaf((float)tv.w, cab.x, cab.y) + xw.w));
            *(float4*)(out + idx) = yv;
        }
    }
}

// ---------------------------------------------------------------- launch
extern "C" void kernel_launch(void* const* d_in, const int* in_sizes, int n_in,
                              void* d_out, int out_size, void* d_ws, size_t ws_size,
                              hipStream_t stream) {
    const float* x  = (const float*)d_in[0];
    const float* w1 = (const float*)d_in[1];
    const float* g1 = (const float*)d_in[2];
    const float* b1 = (const float*)d_in[3];
    const float* w2 = (const float*)d_in[4];
    const float* g2 = (const float*)d_in[5];
    const float* b2 = (const float*)d_in[6];
    float* out = (float*)d_out;
    char* ws = (char*)d_ws;

    constexpr size_t SZ_PAD   = (size_t)Nn * HPAD * WPAD * sizeof(u64);  // 4,326,400 B
    constexpr size_t OFF_YPAD = SZ_PAD;
    constexpr size_t OFF_STAT = 2 * SZ_PAD;                   // 4 arrays of NBIN*64 u64
    constexpr size_t SZ_STAT  = (size_t)NBIN * 64 * 8;        // 8192 B
    constexpr size_t OFF_W1B  = OFF_STAT + 4 * SZ_STAT;
    constexpr size_t OFF_W2B  = OFF_W1B + 576 * 8;
    constexpr size_t OFF_V16  = OFF_W2B + 576 * 8;
    constexpr size_t SZ_V16   = (size_t)Nn * Hh * Ww * 64 * 2; // 64 MiB
    constexpr size_t WS_SMALL = OFF_V16;
    constexpr size_t WS_FULL  = OFF_V16 + SZ_V16;

    if (ws_size < WS_SMALL) return;
    bool spill = (ws_size >= WS_FULL);

    u64* xpad = (u64*)(ws);
    u64* ypad = (u64*)(ws + OFF_YPAD);
    u64* stats = (u64*)(ws + OFF_STAT);
    u64* gsum1 = (u64*)(ws + OFF_STAT);
    u64* gsq1  = (u64*)(ws + OFF_STAT + SZ_STAT);
    u64* gsum2 = (u64*)(ws + OFF_STAT + 2 * SZ_STAT);
    u64* gsq2  = (u64*)(ws + OFF_STAT + 3 * SZ_STAT);
    u64* w1b  = (u64*)(ws + OFF_W1B);
    u64* w2b  = (u64*)(ws + OFF_W2B);
    short* v16 = (short*)(ws + OFF_V16);

    prep_kernel<<<530, 256, 0, stream>>>(x, w1, w2, xpad, ypad, w1b, w2b, stats);
    if (spill) {
        conv_statsT<true><<<4096, 128, 0, stream>>>(xpad, w1b, gsum1, gsq1, v16);
        signpack_v<<<2048, 256, 0, stream>>>(v16, gsum1, gsq1, g1, b1, ypad);
    } else {
        conv_statsT<false><<<4096, 128, 0, stream>>>(xpad, w1b, gsum1, gsq1, nullptr);
        signpack_h<<<4096, 128, 0, stream>>>(xpad, w1b, gsum1, gsq1, g1, b1, ypad);
    }
    conv_statsT<false><<<4096, 128, 0, stream>>>(ypad, w2b, gsum2, gsq2, nullptr);
    final9_kernel<<<4096, 128, 0, stream>>>(ypad, w2b, gsum2, gsq2, g2, b2, x, out);
}

// Round 16
// 205.854 us; speedup vs baseline: 1.1172x; 1.1172x over previous
//
#include <hip/hip_runtime.h>
#include <stdint.h>

typedef unsigned long long u64;
typedef unsigned int u32;

#define Nn 32
#define Cc 64
#define Hh 128
#define Ww 128
#define HPAD 130
#define WPAD 130
#define NHW_TOT (Nn*Hh*Ww)
#define NBIN 16

// ---------------------------------------------------------------- BN finalize (in-kernel, per-lane c)
__device__ __forceinline__ float2 compute_ab(const u64* __restrict__ sum, const u64* __restrict__ sq,
        const float* __restrict__ g, const float* __restrict__ bet, int c) {
    long long Sv = 0, Qv = 0;
    #pragma unroll
    for (int b = 0; b < NBIN; ++b) {
        Sv += (long long)sum[b * 64 + c];
        Qv += (long long)sq[b * 64 + c];
    }
    double mean = (double)Sv / (double)NHW_TOT;
    double var = (double)Qv / (double)NHW_TOT - mean * mean;
    double invstd = 1.0 / sqrt(var + 1e-5);
    double a = (double)g[c] * invstd;
    double b_ = (double)bet[c] - a * mean;
    return make_float2((float)a, (float)b_);
}

// ---------------------------------------------------------------- prep: pack_x (blocks<512) + pack_w + zeroing
#define BORDER_PER_IMG 516              // 2*130 (top+bottom rows) + 2*128 (side cols)
#define BORDER_TOT (Nn * BORDER_PER_IMG)
#define PREP_EXTRA (1152 + 2 * BORDER_TOT + 4 * NBIN * 64)

__global__ __launch_bounds__(256) void prep_kernel(const float* __restrict__ x,
        const float* __restrict__ w1, const float* __restrict__ w2,
        u64* __restrict__ xpad, u64* __restrict__ ypad,
        u64* __restrict__ w1b, u64* __restrict__ w2b, u64* __restrict__ stats) {
    if (blockIdx.x < 512) {
        // ---- pack sign(x) -> u64/pixel, float4 loads
        int t = blockIdx.x * 256 + threadIdx.x;
        int P = t * 4;
        int row = P >> 7, w0 = P & 127;
        int n = row >> 7, h = row & 127;
        const float4* xp4 = (const float4*)(x + ((size_t)n * Cc * Hh + h) * Ww + w0);
        u32 lo0 = 0, lo1 = 0, lo2 = 0, lo3 = 0, hi0 = 0, hi1 = 0, hi2 = 0, hi3 = 0;
        #pragma unroll 8
        for (int c = 0; c < 32; ++c) {
            float4 v = xp4[c * (Hh * Ww / 4)];
            lo0 |= (__float_as_uint(v.x) >> 31) << c;
            lo1 |= (__float_as_uint(v.y) >> 31) << c;
            lo2 |= (__float_as_uint(v.z) >> 31) << c;
            lo3 |= (__float_as_uint(v.w) >> 31) << c;
        }
        #pragma unroll 8
        for (int c = 32; c < 64; ++c) {
            float4 v = xp4[c * (Hh * Ww / 4)];
            hi0 |= (__float_as_uint(v.x) >> 31) << (c - 32);
            hi1 |= (__float_as_uint(v.y) >> 31) << (c - 32);
            hi2 |= (__float_as_uint(v.z) >> 31) << (c - 32);
            hi3 |= (__float_as_uint(v.w) >> 31) << (c - 32);
        }
        u64* dst = xpad + ((size_t)n * HPAD + h + 1) * WPAD + w0 + 1;
        dst[0] = ((u64)hi0 << 32) | lo0;
        dst[1] = ((u64)hi1 << 32) | lo1;
        dst[2] = ((u64)hi2 << 32) | lo2;
        dst[3] = ((u64)hi3 << 32) | lo3;
    } else {
        // ---- grid-stride over: weight packing (1152) + border/stat zeroing
        int t = (blockIdx.x - 512) * 256 + threadIdx.x;
        int stride = (gridDim.x - 512) * 256;
        for (int i = t; i < PREP_EXTRA; i += stride) {
            if (i < 1152) {
                int set = i / 576, idx = i - set * 576;
                const float* src = set ? w2 : w1;
                u64* db = set ? w2b : w1b;
                int co = idx / 9, tap = idx - co * 9;            // co-stride 576
                const float* p = src + (size_t)co * 576 + tap;   // [co][ci][kh][kw], ci stride 9
                u32 lo = 0, hi = 0;
                #pragma unroll
                for (int ci = 0; ci < 32; ++ci)
                    lo |= (__float_as_uint(p[ci * 9]) >> 31) << ci;
                #pragma unroll
                for (int ci = 32; ci < 64; ++ci)
                    hi |= (__float_as_uint(p[ci * 9]) >> 31) << (ci - 32);
                db[idx] = ((u64)hi << 32) | lo;
            } else if (i < 1152 + 2 * BORDER_TOT) {
                int z = i - 1152;
                u64* buf = (z < BORDER_TOT) ? xpad : ypad;
                int k = (z < BORDER_TOT) ? z : z - BORDER_TOT;
                int img = k / BORDER_PER_IMG, j = k - img * BORDER_PER_IMG;
                size_t base = (size_t)img * HPAD * WPAD;
                size_t off;
                if (j < 130)      off = j;                                     // row 0
                else if (j < 260) off = (size_t)(HPAD - 1) * WPAD + (j - 130); // row 129
                else {
                    int k2 = j - 260;
                    off = (size_t)(1 + (k2 >> 1)) * WPAD + ((k2 & 1) ? (WPAD - 1) : 0);
                }
                buf[base + off] = 0ull;
            } else {
                stats[i - 1152 - 2 * BORDER_TOT] = 0ull;
            }
        }
    }
}

// ---------------------------------------------------------------- conv core: lane = co, b128 window loads
__device__ __forceinline__ void conv4(const u64* __restrict__ L0, const u64* __restrict__ L1,
                                      const u64* __restrict__ L2, int w,
                                      const u64 W[9], int corrMid, int v[4]) {
    u64 a[6], b[6], c[6];
    #pragma unroll
    for (int j = 0; j < 3; ++j) {       // 9 x ds_read_b128 instead of 18 x b64
        ulonglong2 pa = *(const ulonglong2*)&L0[w + 2 * j];
        ulonglong2 pb = *(const ulonglong2*)&L1[w + 2 * j];
        ulonglong2 pc = *(const ulonglong2*)&L2[w + 2 * j];
        a[2 * j] = pa.x; a[2 * j + 1] = pa.y;
        b[2 * j] = pb.x; b[2 * j + 1] = pb.y;
        c[2 * j] = pc.x; c[2 * j + 1] = pc.y;
    }
    #pragma unroll
    for (int px = 0; px < 4; ++px) {
        int p0 = __popcll(a[px] ^ W[0]) + __popcll(a[px + 1] ^ W[1]) + __popcll(a[px + 2] ^ W[2]);
        int p1 = __popcll(b[px] ^ W[3]) + __popcll(b[px + 1] ^ W[4]) + __popcll(b[px + 2] ^ W[5]);
        int p2 = __popcll(c[px] ^ W[6]) + __popcll(c[px + 1] ^ W[7]) + __popcll(c[px + 2] ^ W[8]);
        v[px] = 576 - 2 * (p0 + p1 + p2) - corrMid;
    }
}

struct LaneCtx {
    u64 W[9];
    int corrMid, corrW0, corrW127;
};

__device__ __forceinline__ void lane_setup(LaneCtx& C, const u64* __restrict__ wb,
                                           int lane, int h) {
    #pragma unroll
    for (int t = 0; t < 9; ++t) C.W[t] = wb[lane * 9 + t];
    int wc[9];
    #pragma unroll
    for (int t = 0; t < 9; ++t) wc[t] = 64 - 2 * __popcll(C.W[t]);
    int tT = wc[0] + wc[1] + wc[2], tB = wc[6] + wc[7] + wc[8];
    int tL = wc[0] + wc[3] + wc[6], tR = wc[2] + wc[5] + wc[8];
    bool fT = (h == 0), fB = (h == 127);
    C.corrMid  = (fT ? tT : 0) + (fB ? tB : 0);
    C.corrW0   = tL - (fT ? wc[0] : 0) - (fB ? wc[6] : 0);
    C.corrW127 = tR - (fT ? wc[2] : 0) - (fB ? wc[8] : 0);
}

// common half-row window load: rows hp*2..hp*2+3, cols half*64..half*64+65
__device__ __forceinline__ void load_win(u64* __restrict__ win, const u64* __restrict__ inpad,
                                         int n, int hp, int half, int tid) {
    const u64* src = inpad + ((size_t)n * HPAD + hp * 2) * WPAD + half * 64;
    for (int i = tid; i < 264; i += 128) {
        int r = i / 66, c = i - r * 66;
        win[r * 68 + c] = src[(size_t)r * WPAD + c];
    }
}

// ---------------------------------------------------------------- conv + exact BN stats (+ optional v16 spill)
// block = 128 threads = 2 waves; wave = half-row (64 px). blk = n*128 + hp*2 + half
template<bool SPILL>
__global__ __launch_bounds__(128) void conv_statsT(const u64* __restrict__ inpad,
        const u64* __restrict__ wb, u64* __restrict__ gsum, u64* __restrict__ gsq,
        short* __restrict__ v16) {
    __shared__ u64 win[4 * 68];
    __shared__ int r32[256];
    int tid = threadIdx.x;
    int lane = tid & 63;
    int wv = __builtin_amdgcn_readfirstlane(tid >> 6);   // 0/1
    int blk = blockIdx.x;
    int half = blk & 1;
    int hp = (blk >> 1) & 63;
    int n = blk >> 7;
    int h = hp * 2 + wv;
    load_win(win, inpad, n, hp, half, tid);
    LaneCtx C;
    lane_setup(C, wb, lane, h);
    __syncthreads();
    const u64* L0 = &win[wv * 68];
    const u64* L1 = L0 + 68;
    const u64* L2 = L0 + 136;
    short* vrow = SPILL ? (v16 + (((size_t)(n * Hh + h) * Ww) + half * 64) * 64 + lane) : nullptr;
    int s = 0, q = 0;
    for (int w = 0; w < 64; w += 4) {
        int v[4];
        conv4(L0, L1, L2, w, C.W, C.corrMid, v);
        if (half == 0 && w == 0)  v[0] -= C.corrW0;
        if (half == 1 && w == 60) v[3] -= C.corrW127;
        #pragma unroll
        for (int px = 0; px < 4; ++px) {
            s += v[px];
            q += __mul24(v[px], v[px]);
            if (SPILL) vrow[(size_t)(w + px) * 64] = (short)v[px];
        }
    }
    __syncthreads();
    r32[wv * 64 + lane] = s;
    r32[128 + wv * 64 + lane] = q;
    __syncthreads();
    if (wv == 0) {
        int S = r32[lane] + r32[64 + lane];
        int Q = r32[128 + lane] + r32[192 + lane];
        int bin = blk & (NBIN - 1);
        atomicAdd(&gsum[bin * 64 + lane], (u64)(long long)S);
        atomicAdd(&gsq[bin * 64 + lane], (u64)(long long)Q);
    }
}

// ---------------------------------------------------------------- sign(bn1(v16)) -> ballot pack (memory pass)
// block = 256 th = 4 waves; wave = half-row. blk covers rows blk*2, blk*2+1
__global__ __launch_bounds__(256) void signpack_v(const short* __restrict__ v16,
        const u64* __restrict__ sum, const u64* __restrict__ sq,
        const float* __restrict__ g, const float* __restrict__ bet,
        u64* __restrict__ ypad) {
    int tid = threadIdx.x;
    int lane = tid & 63;
    int wv = tid >> 6;
    int grow = blockIdx.x * 2 + (wv >> 1);
    int base = (wv & 1) * 64;
    int n = grow >> 7, h = grow & 127;
    float2 ab = compute_ab(sum, sq, g, bet, lane);
    const short* vr = v16 + ((size_t)grow * Ww + base) * 64;
    u64* drow = ypad + ((size_t)n * HPAD + h + 1) * WPAD + 1;
    u64 myw = 0;
    #pragma unroll 8
    for (int px = 0; px < 64; ++px) {
        float tv = fmaf((float)vr[(size_t)px * 64 + lane], ab.x, ab.y);
        u64 bal = __ballot(tv < 0.0f);
        if (lane == px) myw = bal;
    }
    drow[base + lane] = myw;
}

// ---------------------------------------------------------------- fallback: conv1 recompute signpack (no spill)
__global__ __launch_bounds__(128) void signpack_h(const u64* __restrict__ inpad,
        const u64* __restrict__ wb, const u64* __restrict__ sum, const u64* __restrict__ sq,
        const float* __restrict__ g, const float* __restrict__ bet,
        u64* __restrict__ ypad) {
    __shared__ u64 win[4 * 68];
    int tid = threadIdx.x;
    int lane = tid & 63;
    int wv = __builtin_amdgcn_readfirstlane(tid >> 6);
    int blk = blockIdx.x;
    int half = blk & 1;
    int hp = (blk >> 1) & 63;
    int n = blk >> 7;
    int h = hp * 2 + wv;
    load_win(win, inpad, n, hp, half, tid);
    LaneCtx C;
    lane_setup(C, wb, lane, h);
    float2 ab = compute_ab(sum, sq, g, bet, lane);
    __syncthreads();
    const u64* L0 = &win[wv * 68];
    const u64* L1 = L0 + 68;
    const u64* L2 = L0 + 136;
    u64 myw = 0;
    for (int w = 0; w < 64; w += 4) {
        int v[4];
        conv4(L0, L1, L2, w, C.W, C.corrMid, v);
        if (half == 0 && w == 0)  v[0] -= C.corrW0;
        if (half == 1 && w == 60) v[3] -= C.corrW127;
        #pragma unroll
        for (int px = 0; px < 4; ++px) {
            float t = fmaf((float)v[px], ab.x, ab.y);
            u64 bal = __ballot(t < 0.0f);
            if (lane == w + px) myw = bal;
        }
    }
    ypad[((size_t)n * HPAD + h + 1) * WPAD + 1 + half * 64 + lane] = myw;
}

// ---------------------------------------------------------------- final from spilled conv2 (pure memory pass)
// reads v16 (conv2 outputs) coalesced, stages via LDS tile, flush = bn2+residual+hardtanh
// with per-chunk x-preload (proven in final8). No conv, no window staging.
__global__ __launch_bounds__(128) void final_v_kernel(const short* __restrict__ v16,
        const u64* __restrict__ sum, const u64* __restrict__ sq,
        const float* __restrict__ g, const float* __restrict__ bet,
        const float* __restrict__ x, float* __restrict__ out) {
    __shared__ short T[2][64 * 36];
    __shared__ float2 absh[64];
    int tid = threadIdx.x;
    int lane = tid & 63;
    int wv = __builtin_amdgcn_readfirstlane(tid >> 6);
    int blk = blockIdx.x;
    int half = blk & 1;
    int hp = (blk >> 1) & 63;
    int n = blk >> 7;
    int h = hp * 2 + wv;
    if (tid < 64) absh[tid] = compute_ab(sum, sq, g, bet, tid);
    __syncthreads();
    short* Tw = T[wv];
    int p4 = lane & 7;
    int cosub = lane >> 3;
    size_t base_nch = ((size_t)n * Cc * Hh + h) * Ww;
    const short* vr = v16 + (((size_t)(n * Hh + h) * Ww) + half * 64) * 64 + lane;
    #pragma unroll
    for (int chunk = 0; chunk < 2; ++chunk) {
        int w0 = chunk * 32;
        int w0g = half * 64 + w0;
        // ---- issue-early: all 8 x-loads for this chunk (in flight during v16 reads)
        float4 xv[8];
        size_t xidx[8];
        #pragma unroll
        for (int st = 0; st < 8; ++st) {
            int co = st * 8 + cosub;
            xidx[st] = base_nch + (size_t)co * (Hh * Ww) + w0g + p4 * 4;
            xv[st] = *(const float4*)(x + xidx[st]);
        }
        // ---- read the chunk's conv2 values (lane = co, coalesced 128B/instr)
        #pragma unroll 8
        for (int w = w0; w < w0 + 32; w += 4) {
            short4 sv;
            sv.x = vr[(size_t)(w + 0) * 64];
            sv.y = vr[(size_t)(w + 1) * 64];
            sv.z = vr[(size_t)(w + 2) * 64];
            sv.w = vr[(size_t)(w + 3) * 64];
            *(short4*)&Tw[lane * 36 + (w & 31)] = sv;
        }
        // ---- flush with preloaded x
        #pragma unroll 8
        for (int st = 0; st < 8; ++st) {
            int co = st * 8 + cosub;
            short4 tv = *(const short4*)&Tw[co * 36 + p4 * 4];
            float2 cab = absh[co];
            float4 yv;
            yv.x = fminf(1.0f, fmaxf(-1.0f, fmaf((float)tv.x, cab.x, cab.y) + xv[st].x));
            yv.y = fminf(1.0f, fmaxf(-1.0f, fmaf((float)tv.y, cab.x, cab.y) + xv[st].y));
            yv.z = fminf(1.0f, fmaxf(-1.0f, fmaf((float)tv.z, cab.x, cab.y) + xv[st].z));
            yv.w = fminf(1.0f, fmaxf(-1.0f, fmaf((float)tv.w, cab.x, cab.y) + xv[st].w));
            *(float4*)(out + xidx[st]) = yv;
        }
    }
}

// ---------------------------------------------------------------- fallback: conv2 recompute final (no spill)
__global__ __launch_bounds__(128) void final8_kernel(const u64* __restrict__ inpad,
        const u64* __restrict__ wb, const u64* __restrict__ sum, const u64* __restrict__ sq,
        const float* __restrict__ g, const float* __restrict__ bet,
        const float* __restrict__ x, float* __restrict__ out) {
    __shared__ u64 win[4 * 68];
    __shared__ short T[2][64 * 36];
    __shared__ float2 absh[64];
    int tid = threadIdx.x;
    int lane = tid & 63;
    int wv = __builtin_amdgcn_readfirstlane(tid >> 6);
    int blk = blockIdx.x;
    int half = blk & 1;
    int hp = (blk >> 1) & 63;
    int n = blk >> 7;
    int h = hp * 2 + wv;
    load_win(win, inpad, n, hp, half, tid);
    LaneCtx C;
    lane_setup(C, wb, lane, h);
    if (tid < 64) absh[tid] = compute_ab(sum, sq, g, bet, tid);
    __syncthreads();
    const u64* L0 = &win[wv * 68];
    const u64* L1 = L0 + 68;
    const u64* L2 = L0 + 136;
    short* Tw = T[wv];
    int p4 = lane & 7;
    int cosub = lane >> 3;
    size_t base_nch = ((size_t)n * Cc * Hh + h) * Ww;
    #pragma unroll
    for (int chunk = 0; chunk < 2; ++chunk) {
        int w0 = chunk * 32;
        int w0g = half * 64 + w0;
        float4 xv[8];
        size_t xidx[8];
        #pragma unroll
        for (int st = 0; st < 8; ++st) {
            int co = st * 8 + cosub;
            xidx[st] = base_nch + (size_t)co * (Hh * Ww) + w0g + p4 * 4;
            xv[st] = *(const float4*)(x + xidx[st]);
        }
        for (int w = w0; w < w0 + 32; w += 4) {
            int v[4];
            conv4(L0, L1, L2, w, C.W, C.corrMid, v);
            if (half == 0 && w == 0)  v[0] -= C.corrW0;
            if (half == 1 && w == 60) v[3] -= C.corrW127;
            short4 sv;
            sv.x = (short)v[0]; sv.y = (short)v[1]; sv.z = (short)v[2]; sv.w = (short)v[3];
            *(short4*)&Tw[lane * 36 + (w & 31)] = sv;
        }
        #pragma unroll 8
        for (int st = 0; st < 8; ++st) {
            int co = st * 8 + cosub;
            short4 tv = *(const short4*)&Tw[co * 36 + p4 * 4];
            float2 cab = absh[co];
            float4 yv;
            yv.x = fminf(1.0f, fmaxf(-1.0f, fmaf((float)tv.x, cab.x, cab.y) + xv[st].x));
            yv.y = fminf(1.0f, fmaxf(-1.0f, fmaf((float)tv.y, cab.x, cab.y) + xv[st].y));
            yv.z = fminf(1.0f, fmaxf(-1.0f, fmaf((float)tv.z, cab.x, cab.y) + xv[st].z));
            yv.w = fminf(1.0f, fmaxf(-1.0f, fmaf((float)tv.w, cab.x, cab.y) + xv[st].w));
            *(float4*)(out + xidx[st]) = yv;
        }
    }
}

// ---------------------------------------------------------------- launch
extern "C" void kernel_launch(void* const* d_in, const int* in_sizes, int n_in,
                              void* d_out, int out_size, void* d_ws, size_t ws_size,
                              hipStream_t stream) {
    const float* x  = (const float*)d_in[0];
    const float* w1 = (const float*)d_in[1];
    const float* g1 = (const float*)d_in[2];
    const float* b1 = (const float*)d_in[3];
    const float* w2 = (const float*)d_in[4];
    const float* g2 = (const float*)d_in[5];
    const float* b2 = (const float*)d_in[6];
    float* out = (float*)d_out;
    char* ws = (char*)d_ws;

    constexpr size_t SZ_PAD   = (size_t)Nn * HPAD * WPAD * sizeof(u64);  // 4,326,400 B
    constexpr size_t OFF_YPAD = SZ_PAD;
    constexpr size_t OFF_STAT = 2 * SZ_PAD;                   // 4 arrays of NBIN*64 u64
    constexpr size_t SZ_STAT  = (size_t)NBIN * 64 * 8;        // 8192 B
    constexpr size_t OFF_W1B  = OFF_STAT + 4 * SZ_STAT;
    constexpr size_t OFF_W2B  = OFF_W1B + 576 * 8;
    constexpr size_t OFF_V16  = OFF_W2B + 576 * 8;
    constexpr size_t SZ_V16   = (size_t)Nn * Hh * Ww * 64 * 2; // 64 MiB (reused: conv1 spill, then conv2 spill)
    constexpr size_t WS_SMALL = OFF_V16;
    constexpr size_t WS_FULL  = OFF_V16 + SZ_V16;

    if (ws_size < WS_SMALL) return;
    bool spill = (ws_size >= WS_FULL);

    u64* xpad = (u64*)(ws);
    u64* ypad = (u64*)(ws + OFF_YPAD);
    u64* stats = (u64*)(ws + OFF_STAT);
    u64* gsum1 = (u64*)(ws + OFF_STAT);
    u64* gsq1  = (u64*)(ws + OFF_STAT + SZ_STAT);
    u64* gsum2 = (u64*)(ws + OFF_STAT + 2 * SZ_STAT);
    u64* gsq2  = (u64*)(ws + OFF_STAT + 3 * SZ_STAT);
    u64* w1b  = (u64*)(ws + OFF_W1B);
    u64* w2b  = (u64*)(ws + OFF_W2B);
    short* v16 = (short*)(ws + OFF_V16);

    prep_kernel<<<530, 256, 0, stream>>>(x, w1, w2, xpad, ypad, w1b, w2b, stats);
    if (spill) {
        conv_statsT<true><<<4096, 128, 0, stream>>>(xpad, w1b, gsum1, gsq1, v16);
        signpack_v<<<2048, 256, 0, stream>>>(v16, gsum1, gsq1, g1, b1, ypad);
        // v16 is dead after signpack_v: stats2 reuses it for conv2 outputs
        conv_statsT<true><<<4096, 128, 0, stream>>>(ypad, w2b, gsum2, gsq2, v16);
        final_v_kernel<<<4096, 128, 0, stream>>>(v16, gsum2, gsq2, g2, b2, x, out);
    } else {
        conv_statsT<false><<<4096, 128, 0, stream>>>(xpad, w1b, gsum1, gsq1, nullptr);
        signpack_h<<<4096, 128, 0, stream>>>(xpad, w1b, gsum1, gsq1, g1, b1, ypad);
        conv_statsT<false><<<4096, 128, 0, stream>>>(ypad, w2b, gsum2, gsq2, nullptr);
        final8_kernel<<<4096, 128, 0, stream>>>(ypad, w2b, gsum2, gsq2, g2, b2, x, out);
    }
}

// Round 17
// 202.268 us; speedup vs baseline: 1.1370x; 1.0177x over previous
//
#include <hip/hip_runtime.h>
#include <stdint.h>

typedef unsigned long long u64;
typedef unsigned int u32;

#define Nn 32
#define Cc 64
#define Hh 128
#define Ww 128
#define HPAD 130
#define WPAD 130
#define NHW_TOT (Nn*Hh*Ww)
#define NBIN 16

// ---------------------------------------------------------------- BN finalize (in-kernel, per-lane c)
__device__ __forceinline__ float2 compute_ab(const u64* __restrict__ sum, const u64* __restrict__ sq,
        const float* __restrict__ g, const float* __restrict__ bet, int c) {
    long long Sv = 0, Qv = 0;
    #pragma unroll
    for (int b = 0; b < NBIN; ++b) {
        Sv += (long long)sum[b * 64 + c];
        Qv += (long long)sq[b * 64 + c];
    }
    double mean = (double)Sv / (double)NHW_TOT;
    double var = (double)Qv / (double)NHW_TOT - mean * mean;
    double invstd = 1.0 / sqrt(var + 1e-5);
    double a = (double)g[c] * invstd;
    double b_ = (double)bet[c] - a * mean;
    return make_float2((float)a, (float)b_);
}

// ---------------------------------------------------------------- prep: pack_x (blocks<512) + pack_w + zeroing
#define BORDER_PER_IMG 516              // 2*130 (top+bottom rows) + 2*128 (side cols)
#define BORDER_TOT (Nn * BORDER_PER_IMG)
#define PREP_EXTRA (1152 + 2 * BORDER_TOT + 4 * NBIN * 64)

__global__ __launch_bounds__(256) void prep_kernel(const float* __restrict__ x,
        const float* __restrict__ w1, const float* __restrict__ w2,
        u64* __restrict__ xpad, u64* __restrict__ ypad,
        u64* __restrict__ w1b, u64* __restrict__ w2b, u64* __restrict__ stats) {
    if (blockIdx.x < 512) {
        // ---- pack sign(x) -> u64/pixel, float4 loads
        int t = blockIdx.x * 256 + threadIdx.x;
        int P = t * 4;
        int row = P >> 7, w0 = P & 127;
        int n = row >> 7, h = row & 127;
        const float4* xp4 = (const float4*)(x + ((size_t)n * Cc * Hh + h) * Ww + w0);
        u32 lo0 = 0, lo1 = 0, lo2 = 0, lo3 = 0, hi0 = 0, hi1 = 0, hi2 = 0, hi3 = 0;
        #pragma unroll 8
        for (int c = 0; c < 32; ++c) {
            float4 v = xp4[c * (Hh * Ww / 4)];
            lo0 |= (__float_as_uint(v.x) >> 31) << c;
            lo1 |= (__float_as_uint(v.y) >> 31) << c;
            lo2 |= (__float_as_uint(v.z) >> 31) << c;
            lo3 |= (__float_as_uint(v.w) >> 31) << c;
        }
        #pragma unroll 8
        for (int c = 32; c < 64; ++c) {
            float4 v = xp4[c * (Hh * Ww / 4)];
            hi0 |= (__float_as_uint(v.x) >> 31) << (c - 32);
            hi1 |= (__float_as_uint(v.y) >> 31) << (c - 32);
            hi2 |= (__float_as_uint(v.z) >> 31) << (c - 32);
            hi3 |= (__float_as_uint(v.w) >> 31) << (c - 32);
        }
        u64* dst = xpad + ((size_t)n * HPAD + h + 1) * WPAD + w0 + 1;
        dst[0] = ((u64)hi0 << 32) | lo0;
        dst[1] = ((u64)hi1 << 32) | lo1;
        dst[2] = ((u64)hi2 << 32) | lo2;
        dst[3] = ((u64)hi3 << 32) | lo3;
    } else {
        // ---- grid-stride over: weight packing (1152) + border/stat zeroing
        int t = (blockIdx.x - 512) * 256 + threadIdx.x;
        int stride = (gridDim.x - 512) * 256;
        for (int i = t; i < PREP_EXTRA; i += stride) {
            if (i < 1152) {
                int set = i / 576, idx = i - set * 576;
                const float* src = set ? w2 : w1;
                u64* db = set ? w2b : w1b;
                int co = idx / 9, tap = idx - co * 9;            // co-stride 576
                const float* p = src + (size_t)co * 576 + tap;   // [co][ci][kh][kw], ci stride 9
                u32 lo = 0, hi = 0;
                #pragma unroll
                for (int ci = 0; ci < 32; ++ci)
                    lo |= (__float_as_uint(p[ci * 9]) >> 31) << ci;
                #pragma unroll
                for (int ci = 32; ci < 64; ++ci)
                    hi |= (__float_as_uint(p[ci * 9]) >> 31) << (ci - 32);
                db[idx] = ((u64)hi << 32) | lo;
            } else if (i < 1152 + 2 * BORDER_TOT) {
                int z = i - 1152;
                u64* buf = (z < BORDER_TOT) ? xpad : ypad;
                int k = (z < BORDER_TOT) ? z : z - BORDER_TOT;
                int img = k / BORDER_PER_IMG, j = k - img * BORDER_PER_IMG;
                size_t base = (size_t)img * HPAD * WPAD;
                size_t off;
                if (j < 130)      off = j;                                     // row 0
                else if (j < 260) off = (size_t)(HPAD - 1) * WPAD + (j - 130); // row 129
                else {
                    int k2 = j - 260;
                    off = (size_t)(1 + (k2 >> 1)) * WPAD + ((k2 & 1) ? (WPAD - 1) : 0);
                }
                buf[base + off] = 0ull;
            } else {
                stats[i - 1152 - 2 * BORDER_TOT] = 0ull;
            }
        }
    }
}

// ---------------------------------------------------------------- conv core: lane = co, b128 window loads
__device__ __forceinline__ void conv4(const u64* __restrict__ L0, const u64* __restrict__ L1,
                                      const u64* __restrict__ L2, int w,
                                      const u64 W[9], int corrMid, int v[4]) {
    u64 a[6], b[6], c[6];
    #pragma unroll
    for (int j = 0; j < 3; ++j) {       // 9 x ds_read_b128 instead of 18 x b64
        ulonglong2 pa = *(const ulonglong2*)&L0[w + 2 * j];
        ulonglong2 pb = *(const ulonglong2*)&L1[w + 2 * j];
        ulonglong2 pc = *(const ulonglong2*)&L2[w + 2 * j];
        a[2 * j] = pa.x; a[2 * j + 1] = pa.y;
        b[2 * j] = pb.x; b[2 * j + 1] = pb.y;
        c[2 * j] = pc.x; c[2 * j + 1] = pc.y;
    }
    #pragma unroll
    for (int px = 0; px < 4; ++px) {
        int p0 = __popcll(a[px] ^ W[0]) + __popcll(a[px + 1] ^ W[1]) + __popcll(a[px + 2] ^ W[2]);
        int p1 = __popcll(b[px] ^ W[3]) + __popcll(b[px + 1] ^ W[4]) + __popcll(b[px + 2] ^ W[5]);
        int p2 = __popcll(c[px] ^ W[6]) + __popcll(c[px + 1] ^ W[7]) + __popcll(c[px + 2] ^ W[8]);
        v[px] = 576 - 2 * (p0 + p1 + p2) - corrMid;
    }
}

struct LaneCtx {
    u64 W[9];
    int corrMid, corrW0, corrW127;
};

__device__ __forceinline__ void lane_setup(LaneCtx& C, const u64* __restrict__ wb,
                                           int lane, int h) {
    #pragma unroll
    for (int t = 0; t < 9; ++t) C.W[t] = wb[lane * 9 + t];
    int wc[9];
    #pragma unroll
    for (int t = 0; t < 9; ++t) wc[t] = 64 - 2 * __popcll(C.W[t]);
    int tT = wc[0] + wc[1] + wc[2], tB = wc[6] + wc[7] + wc[8];
    int tL = wc[0] + wc[3] + wc[6], tR = wc[2] + wc[5] + wc[8];
    bool fT = (h == 0), fB = (h == 127);
    C.corrMid  = (fT ? tT : 0) + (fB ? tB : 0);
    C.corrW0   = tL - (fT ? wc[0] : 0) - (fB ? wc[6] : 0);
    C.corrW127 = tR - (fT ? wc[2] : 0) - (fB ? wc[8] : 0);
}

// common half-row window load: rows hp*2..hp*2+3, cols half*64..half*64+65
__device__ __forceinline__ void load_win(u64* __restrict__ win, const u64* __restrict__ inpad,
                                         int n, int hp, int half, int tid) {
    const u64* src = inpad + ((size_t)n * HPAD + hp * 2) * WPAD + half * 64;
    for (int i = tid; i < 264; i += 128) {
        int r = i / 66, c = i - r * 66;
        win[r * 68 + c] = src[(size_t)r * WPAD + c];
    }
}

// ---------------------------------------------------------------- conv + exact BN stats (+ optional v16 spill)
// block = 128 threads = 2 waves; wave = half-row (64 px). blk = n*128 + hp*2 + half
template<bool SPILL>
__global__ __launch_bounds__(128) void conv_statsT(const u64* __restrict__ inpad,
        const u64* __restrict__ wb, u64* __restrict__ gsum, u64* __restrict__ gsq,
        short* __restrict__ v16) {
    __shared__ u64 win[4 * 68];
    __shared__ int r32[256];
    int tid = threadIdx.x;
    int lane = tid & 63;
    int wv = __builtin_amdgcn_readfirstlane(tid >> 6);   // 0/1
    int blk = blockIdx.x;
    int half = blk & 1;
    int hp = (blk >> 1) & 63;
    int n = blk >> 7;
    int h = hp * 2 + wv;
    load_win(win, inpad, n, hp, half, tid);
    LaneCtx C;
    lane_setup(C, wb, lane, h);
    __syncthreads();
    const u64* L0 = &win[wv * 68];
    const u64* L1 = L0 + 68;
    const u64* L2 = L0 + 136;
    short* vrow = SPILL ? (v16 + (((size_t)(n * Hh + h) * Ww) + half * 64) * 64 + lane) : nullptr;
    int s = 0, q = 0;
    for (int w = 0; w < 64; w += 4) {
        int v[4];
        conv4(L0, L1, L2, w, C.W, C.corrMid, v);
        if (half == 0 && w == 0)  v[0] -= C.corrW0;
        if (half == 1 && w == 60) v[3] -= C.corrW127;
        #pragma unroll
        for (int px = 0; px < 4; ++px) {
            s += v[px];
            q += __mul24(v[px], v[px]);
            if (SPILL) vrow[(size_t)(w + px) * 64] = (short)v[px];
        }
    }
    __syncthreads();
    r32[wv * 64 + lane] = s;
    r32[128 + wv * 64 + lane] = q;
    __syncthreads();
    if (wv == 0) {
        int S = r32[lane] + r32[64 + lane];
        int Q = r32[128 + lane] + r32[192 + lane];
        int bin = blk & (NBIN - 1);
        atomicAdd(&gsum[bin * 64 + lane], (u64)(long long)S);
        atomicAdd(&gsq[bin * 64 + lane], (u64)(long long)Q);
    }
}

// ---------------------------------------------------------------- sign(bn1(v16)) -> ballot pack (memory pass)
// block = 256 th = 4 waves; wave = half-row. blk covers rows blk*2, blk*2+1
__global__ __launch_bounds__(256) void signpack_v(const short* __restrict__ v16,
        const u64* __restrict__ sum, const u64* __restrict__ sq,
        const float* __restrict__ g, const float* __restrict__ bet,
        u64* __restrict__ ypad) {
    int tid = threadIdx.x;
    int lane = tid & 63;
    int wv = tid >> 6;
    int grow = blockIdx.x * 2 + (wv >> 1);
    int base = (wv & 1) * 64;
    int n = grow >> 7, h = grow & 127;
    float2 ab = compute_ab(sum, sq, g, bet, lane);
    const short* vr = v16 + ((size_t)grow * Ww + base) * 64;
    u64* drow = ypad + ((size_t)n * HPAD + h + 1) * WPAD + 1;
    u64 myw = 0;
    #pragma unroll 8
    for (int px = 0; px < 64; ++px) {
        float tv = fmaf((float)vr[(size_t)px * 64 + lane], ab.x, ab.y);
        u64 bal = __ballot(tv < 0.0f);
        if (lane == px) myw = bal;
    }
    drow[base + lane] = myw;
}

// ---------------------------------------------------------------- fallback: conv1 recompute signpack (no spill)
__global__ __launch_bounds__(128) void signpack_h(const u64* __restrict__ inpad,
        const u64* __restrict__ wb, const u64* __restrict__ sum, const u64* __restrict__ sq,
        const float* __restrict__ g, const float* __restrict__ bet,
        u64* __restrict__ ypad) {
    __shared__ u64 win[4 * 68];
    int tid = threadIdx.x;
    int lane = tid & 63;
    int wv = __builtin_amdgcn_readfirstlane(tid >> 6);
    int blk = blockIdx.x;
    int half = blk & 1;
    int hp = (blk >> 1) & 63;
    int n = blk >> 7;
    int h = hp * 2 + wv;
    load_win(win, inpad, n, hp, half, tid);
    LaneCtx C;
    lane_setup(C, wb, lane, h);
    float2 ab = compute_ab(sum, sq, g, bet, lane);
    __syncthreads();
    const u64* L0 = &win[wv * 68];
    const u64* L1 = L0 + 68;
    const u64* L2 = L0 + 136;
    u64 myw = 0;
    for (int w = 0; w < 64; w += 4) {
        int v[4];
        conv4(L0, L1, L2, w, C.W, C.corrMid, v);
        if (half == 0 && w == 0)  v[0] -= C.corrW0;
        if (half == 1 && w == 60) v[3] -= C.corrW127;
        #pragma unroll
        for (int px = 0; px < 4; ++px) {
            float t = fmaf((float)v[px], ab.x, ab.y);
            u64 bal = __ballot(t < 0.0f);
            if (lane == w + px) myw = bal;
        }
    }
    ypad[((size_t)n * HPAD + h + 1) * WPAD + 1 + half * 64 + lane] = myw;
}

// ---------------------------------------------------------------- conv2 + bn2 + residual + hardtanh
// final8: x-preload software pipeline per 32-px chunk (proven best, R13)
__global__ __launch_bounds__(128) void final8_kernel(const u64* __restrict__ inpad,
        const u64* __restrict__ wb, const u64* __restrict__ sum, const u64* __restrict__ sq,
        const float* __restrict__ g, const float* __restrict__ bet,
        const float* __restrict__ x, float* __restrict__ out) {
    __shared__ u64 win[4 * 68];
    __shared__ short T[2][64 * 36];
    __shared__ float2 absh[64];
    int tid = threadIdx.x;
    int lane = tid & 63;
    int wv = __builtin_amdgcn_readfirstlane(tid >> 6);
    int blk = blockIdx.x;
    int half = blk & 1;
    int hp = (blk >> 1) & 63;
    int n = blk >> 7;
    int h = hp * 2 + wv;
    load_win(win, inpad, n, hp, half, tid);
    LaneCtx C;
    lane_setup(C, wb, lane, h);
    if (tid < 64) absh[tid] = compute_ab(sum, sq, g, bet, tid);
    __syncthreads();
    const u64* L0 = &win[wv * 68];
    const u64* L1 = L0 + 68;
    const u64* L2 = L0 + 136;
    short* Tw = T[wv];
    int p4 = lane & 7;
    int cosub = lane >> 3;
    size_t base_nch = ((size_t)n * Cc * Hh + h) * Ww;
    #pragma unroll
    for (int chunk = 0; chunk < 2; ++chunk) {
        int w0 = chunk * 32;
        int w0g = half * 64 + w0;
        // ---- issue-early: all 8 x-loads for this chunk (in flight during conv)
        float4 xv[8];
        size_t xidx[8];
        #pragma unroll
        for (int st = 0; st < 8; ++st) {
            int co = st * 8 + cosub;
            xidx[st] = base_nch + (size_t)co * (Hh * Ww) + w0g + p4 * 4;
            xv[st] = *(const float4*)(x + xidx[st]);
        }
        // ---- conv the 32-px chunk into the wave-private tile
        for (int w = w0; w < w0 + 32; w += 4) {
            int v[4];
            conv4(L0, L1, L2, w, C.W, C.corrMid, v);
            if (half == 0 && w == 0)  v[0] -= C.corrW0;
            if (half == 1 && w == 60) v[3] -= C.corrW127;
            short4 sv;
            sv.x = (short)v[0]; sv.y = (short)v[1]; sv.z = (short)v[2]; sv.w = (short)v[3];
            *(short4*)&Tw[lane * 36 + (w & 31)] = sv;
        }
        // ---- use-late: flush with preloaded x
        #pragma unroll 8
        for (int st = 0; st < 8; ++st) {
            int co = st * 8 + cosub;
            short4 tv = *(const short4*)&Tw[co * 36 + p4 * 4];
            float2 cab = absh[co];
            float4 yv;
            yv.x = fminf(1.0f, fmaxf(-1.0f, fmaf((float)tv.x, cab.x, cab.y) + xv[st].x));
            yv.y = fminf(1.0f, fmaxf(-1.0f, fmaf((float)tv.y, cab.x, cab.y) + xv[st].y));
            yv.z = fminf(1.0f, fmaxf(-1.0f, fmaf((float)tv.z, cab.x, cab.y) + xv[st].z));
            yv.w = fminf(1.0f, fmaxf(-1.0f, fmaf((float)tv.w, cab.x, cab.y) + xv[st].w));
            *(float4*)(out + xidx[st]) = yv;
        }
    }
}

// ---------------------------------------------------------------- launch
extern "C" void kernel_launch(void* const* d_in, const int* in_sizes, int n_in,
                              void* d_out, int out_size, void* d_ws, size_t ws_size,
                              hipStream_t stream) {
    const float* x  = (const float*)d_in[0];
    const float* w1 = (const float*)d_in[1];
    const float* g1 = (const float*)d_in[2];
    const float* b1 = (const float*)d_in[3];
    const float* w2 = (const float*)d_in[4];
    const float* g2 = (const float*)d_in[5];
    const float* b2 = (const float*)d_in[6];
    float* out = (float*)d_out;
    char* ws = (char*)d_ws;

    constexpr size_t SZ_PAD   = (size_t)Nn * HPAD * WPAD * sizeof(u64);  // 4,326,400 B
    constexpr size_t OFF_YPAD = SZ_PAD;
    constexpr size_t OFF_STAT = 2 * SZ_PAD;                   // 4 arrays of NBIN*64 u64
    constexpr size_t SZ_STAT  = (size_t)NBIN * 64 * 8;        // 8192 B
    constexpr size_t OFF_W1B  = OFF_STAT + 4 * SZ_STAT;
    constexpr size_t OFF_W2B  = OFF_W1B + 576 * 8;
    constexpr size_t OFF_V16  = OFF_W2B + 576 * 8;
    constexpr size_t SZ_V16   = (size_t)Nn * Hh * Ww * 64 * 2; // 64 MiB
    constexpr size_t WS_SMALL = OFF_V16;
    constexpr size_t WS_FULL  = OFF_V16 + SZ_V16;

    if (ws_size < WS_SMALL) return;
    bool spill = (ws_size >= WS_FULL);

    u64* xpad = (u64*)(ws);
    u64* ypad = (u64*)(ws + OFF_YPAD);
    u64* stats = (u64*)(ws + OFF_STAT);
    u64* gsum1 = (u64*)(ws + OFF_STAT);
    u64* gsq1  = (u64*)(ws + OFF_STAT + SZ_STAT);
    u64* gsum2 = (u64*)(ws + OFF_STAT + 2 * SZ_STAT);
    u64* gsq2  = (u64*)(ws + OFF_STAT + 3 * SZ_STAT);
    u64* w1b  = (u64*)(ws + OFF_W1B);
    u64* w2b  = (u64*)(ws + OFF_W2B);
    short* v16 = (short*)(ws + OFF_V16);

    prep_kernel<<<530, 256, 0, stream>>>(x, w1, w2, xpad, ypad, w1b, w2b, stats);
    if (spill) {
        conv_statsT<true><<<4096, 128, 0, stream>>>(xpad, w1b, gsum1, gsq1, v16);
        signpack_v<<<2048, 256, 0, stream>>>(v16, gsum1, gsq1, g1, b1, ypad);
    } else {
        conv_statsT<false><<<4096, 128, 0, stream>>>(xpad, w1b, gsum1, gsq1, nullptr);
        signpack_h<<<4096, 128, 0, stream>>>(xpad, w1b, gsum1, gsq1, g1, b1, ypad);
    }
    conv_statsT<false><<<4096, 128, 0, stream>>>(ypad, w2b, gsum2, gsq2, nullptr);
    final8_kernel<<<4096, 128, 0, stream>>>(ypad, w2b, gsum2, gsq2, g2, b2, x, out);
}